// Round 9
// baseline (387.320 us; speedup 1.0000x reference)
//
#include <hip/hip_runtime.h>
#include <hip/hip_bf16.h>

// Problem constants (fixed by the reference)
#define BB 2
#define NN 2048
#define KE 48     // neighbors per node
#define CC 128
#define FFD 512
#define K3 384    // 3*C (full weight row stride in WT layout)

// bf16 MFMA fragment types (guide §3, HW-verified m89/m91/m92)
typedef short sx8 __attribute__((ext_vector_type(8)));   // 8 bf16 in 4 VGPRs
typedef float fx4 __attribute__((ext_vector_type(4)));   // 4 fp32 acc

__device__ __forceinline__ short f2bs(float f) {
    __bf16 h = (__bf16)f;            // RNE fp32->bf16
    return __builtin_bit_cast(short, h);
}

// Fast exact-quality GELU: erf via Abramowitz-Stegun 7.1.26, |err|<1.5e-7.
__device__ __forceinline__ float gelu_f(float x) {
    float z = fabsf(x) * 0.70710678118654752f;
    float e = __expf(-z * z);
    float t = __builtin_amdgcn_rcpf(fmaf(0.3275911f, z, 1.0f));
    float poly = t * fmaf(t, fmaf(t, fmaf(t, fmaf(t, 1.061405429f, -1.453152027f),
                                          1.421413741f), -0.284496736f), 0.254829592f);
    float erf = 1.0f - poly * e;
    float phi = fmaf(copysignf(erf, x), 0.5f, 0.5f);
    return x * phi;
}

// load 8 consecutive fp32 (32B aligned) and convert to bf16x8 (as short8)
__device__ __forceinline__ sx8 cvt8f(const float* p) {
    float4 a = *(const float4*)p;
    float4 b = *(const float4*)(p + 4);
    sx8 r;
    r[0] = f2bs(a.x); r[1] = f2bs(a.y); r[2] = f2bs(a.z); r[3] = f2bs(a.w);
    r[4] = f2bs(b.x); r[5] = f2bs(b.y); r[6] = f2bs(b.z); r[7] = f2bs(b.w);
    return r;
}

// pack two float4 (already in registers) to bf16x8
__device__ __forceinline__ sx8 pack8(float4 a, float4 b) {
    sx8 r;
    r[0] = f2bs(a.x); r[1] = f2bs(a.y); r[2] = f2bs(a.z); r[3] = f2bs(a.w);
    r[4] = f2bs(b.x); r[5] = f2bs(b.y); r[6] = f2bs(b.z); r[7] = f2bs(b.w);
    return r;
}

// ---------------------------------------------------------------------------
// Transpose + fp32->bf16 convert the 8 weight matrices into ws (unchanged).
// bf16-elem offsets: W1T@0(128x384) W2T@49152(128x128) W3T@65536
// W11T@81920(128x384) W12T@131072 W13T@147456 WinT@163840(512x128)
// WoutT@229376(128x512); total 294912 elems (576KB); Pc/Pn fp32 follow.
// ---------------------------------------------------------------------------
__global__ void prep_weights(const float* __restrict__ W1, const float* __restrict__ W2,
                             const float* __restrict__ W3, const float* __restrict__ W11,
                             const float* __restrict__ W12, const float* __restrict__ W13,
                             const float* __restrict__ Win, const float* __restrict__ Wout,
                             short* __restrict__ wt) {
    int i = blockIdx.x * 256 + threadIdx.x;  // grid covers exactly 294912
    const float* src;
    short* dst;
    int R, S, local;   // R = inner (k) extent of WT; S = row stride of source
    if (i < 49152)       { src = W1;   dst = wt;          R = 384; S = 128; local = i; }
    else if (i < 65536)  { src = W2;   dst = wt + 49152;  R = 128; S = 128; local = i - 49152; }
    else if (i < 81920)  { src = W3;   dst = wt + 65536;  R = 128; S = 128; local = i - 65536; }
    else if (i < 131072) { src = W11;  dst = wt + 81920;  R = 384; S = 128; local = i - 81920; }
    else if (i < 147456) { src = W12;  dst = wt + 131072; R = 128; S = 128; local = i - 131072; }
    else if (i < 163840) { src = W13;  dst = wt + 147456; R = 128; S = 128; local = i - 147456; }
    else if (i < 229376) { src = Win;  dst = wt + 163840; R = 128; S = 512; local = i - 163840; }
    else                 { src = Wout; dst = wt + 229376; R = 512; S = 128; local = i - 229376; }
    int c = local / R;
    int r = local - c * R;
    dst[local] = f2bs(src[r * S + c]);  // WT[c][r] = W[r][c]
}

// ---------------------------------------------------------------------------
// Precompute node projections for edge pass 1:
//   Pc[n][c] = hv[n] @ W[0:128][c]   + bias[c]     (ctr part of concat, +b)
//   Pn[n][c] = hv[n] @ W[256:384][c]               (nbr part of concat)
// 16 nodes per block, grid 256; wave w covers cols [32w, 32w+32) for both.
// (Pass-2's instance is fused into the tail of ffn_kernel.)
// ---------------------------------------------------------------------------
__global__ __launch_bounds__(256) void precompute_P(
    const float* __restrict__ hv, const short* __restrict__ WT,
    const float* __restrict__ bias, float* __restrict__ Pc,
    float* __restrict__ Pn) {
    __shared__ __align__(16) short Abf[16 * 136];
    const int tid = threadIdx.x;
    const int bn  = blockIdx.x;       // node tile [bn*16, bn*16+16)
    const int wave = tid >> 6, lane = tid & 63, q = lane >> 4, m16 = lane & 15;
    const int col0 = wave * 32 + m16, col1 = col0 + 16;

    {   // stage 16x128 A-tile as bf16: one sx8 per thread
        int row = tid >> 4, seg = tid & 15;
        *(sx8*)(Abf + row * 136 + seg * 8) = cvt8f(hv + (size_t)(bn * 16 + row) * CC + seg * 8);
    }
    __syncthreads();

    fx4 c0, c1, n0, n1;
#pragma unroll
    for (int r = 0; r < 4; ++r) { c0[r] = 0.f; c1[r] = 0.f; n0[r] = 0.f; n1[r] = 0.f; }
#pragma unroll
    for (int kk = 0; kk < 4; ++kk) {
        sx8 af = *(const sx8*)(Abf + m16 * 136 + kk * 32 + q * 8);
        sx8 bc0 = *(const sx8*)(WT + col0 * K3 + kk * 32 + q * 8);
        sx8 bc1 = *(const sx8*)(WT + col1 * K3 + kk * 32 + q * 8);
        sx8 bn0 = *(const sx8*)(WT + col0 * K3 + 256 + kk * 32 + q * 8);
        sx8 bn1 = *(const sx8*)(WT + col1 * K3 + 256 + kk * 32 + q * 8);
        c0 = __builtin_amdgcn_mfma_f32_16x16x32_bf16(af, bc0, c0, 0, 0, 0);
        c1 = __builtin_amdgcn_mfma_f32_16x16x32_bf16(af, bc1, c1, 0, 0, 0);
        n0 = __builtin_amdgcn_mfma_f32_16x16x32_bf16(af, bn0, n0, 0, 0, 0);
        n1 = __builtin_amdgcn_mfma_f32_16x16x32_bf16(af, bn1, n1, 0, 0, 0);
    }
    float bi0 = bias[col0], bi1 = bias[col1];
#pragma unroll
    for (int r = 0; r < 4; ++r) {
        int node = bn * 16 + q * 4 + r;
        Pc[(size_t)node * CC + col0] = c0[r] + bi0;
        Pc[(size_t)node * CC + col1] = c1[r] + bi1;
        Pn[(size_t)node * CC + col0] = n0[r];
        Pn[(size_t)node * CC + col1] = n1[r];
    }
}

// ---------------------------------------------------------------------------
// Edge MLP pass -- R12: R8 kernel (proven 90us, VGPR=48 natural pressure),
// occupancy raised to 6 blocks/CU: cap 85 > measured 48 -> no spill expected.
// LDS 26112B x 6 = 156.7KB <= 160KB.
//   bufA @0 (13056B): hE bf16 tile (GEMM1 A) -> X2 (GEMM3 A).
//   bufB @13056 (13056B): X1 (GEMM2 A) -> dhp/redp (PASS1).
//   S (PASS2, 48x132 fp32 = 25344B) spans both buffers; written post-B4.
// Barriers: 5 both passes.
// ---------------------------------------------------------------------------
template <int PASS>
__global__ __launch_bounds__(256, 6) void edge_pass(
    const float* __restrict__ hVsrc, const float* __restrict__ hE,
    const int* __restrict__ Eidx,
    const short* __restrict__ WaT,
    const short* __restrict__ WbT, const float* __restrict__ Wbb,
    const short* __restrict__ WcT, const float* __restrict__ Wcb,
    const float* __restrict__ Pc, const float* __restrict__ Pn,
    const float* __restrict__ mask_att, float* __restrict__ hv1_out,
    const float* __restrict__ gamma, const float* __restrict__ beta,
    float* __restrict__ hE_out) {
    __shared__ __align__(16) unsigned char smem_raw[26112];
    short* A0   = (short*)smem_raw;                    // bufA: hE tile -> X2
    short* X1   = (short*)(smem_raw + 13056);          // bufB: X1 -> scratch
    float* S    = (float*)smem_raw;                    // PASS2 LN (spans both)
    float* dhp  = (float*)(smem_raw + 13056);          // PASS1: 512 floats
    float* redp = (float*)(smem_raw + 13056 + 2048);   // PASS1: 4 floats

    const int tid = threadIdx.x;
    const int bn  = blockIdx.x;       // b*N+n
    const int bb  = bn >> 11;         // batch (N=2048)
    const int wave = tid >> 6, lane = tid & 63, q = lane >> 4, m16 = lane & 15;
    const int col0 = wave * 32 + m16; // ntile 2*wave
    const int col1 = col0 + 16;       // ntile 2*wave+1
    const int r0 = tid >> 4, seg = tid & 15;

    // ---- Eidx for this lane's 12 acc rows (row = mt*16 + q*4 + r) ----
    int e[3][4];
#pragma unroll
    for (int mt = 0; mt < 3; ++mt)
#pragma unroll
        for (int r = 0; r < 4; ++r)
            e[mt][r] = Eidx[bn * KE + mt * 16 + q * 4 + r];

    // ---- Pc / Pn gathers: issued now, consumed at epilogue 1 ----
    float pc0 = Pc[(size_t)bn * CC + col0];
    float pc1 = Pc[(size_t)bn * CC + col1];
    float pn0[3][4], pn1[3][4];
#pragma unroll
    for (int mt = 0; mt < 3; ++mt)
#pragma unroll
        for (int r = 0; r < 4; ++r) {
            size_t prow = ((size_t)bb * NN + e[mt][r]) * CC;
            pn0[mt][r] = Pn[prow + col0];
            pn1[mt][r] = Pn[prow + col1];
        }

    // ---- stage A0 = hE tile (3 rows/thread, 6 float4 loads batched) ----
    {
        const float* he = hE + (size_t)bn * KE * CC + seg * 8;
        float4 h0a = *(const float4*)(he + r0 * CC);
        float4 h0b = *(const float4*)(he + r0 * CC + 4);
        float4 h1a = *(const float4*)(he + (r0 + 16) * CC);
        float4 h1b = *(const float4*)(he + (r0 + 16) * CC + 4);
        float4 h2a = *(const float4*)(he + (r0 + 32) * CC);
        float4 h2b = *(const float4*)(he + (r0 + 32) * CC + 4);
        *(sx8*)(A0 + r0 * 136 + seg * 8)        = pack8(h0a, h0b);
        *(sx8*)(A0 + (r0 + 16) * 136 + seg * 8) = pack8(h1a, h1b);
        *(sx8*)(A0 + (r0 + 32) * 136 + seg * 8) = pack8(h2a, h2b);
    }

    // ---- prefetch GEMM1 B-frags: W1 rows 128..255 (hE block) ----
    sx8 b0[4], b1[4];
#pragma unroll
    for (int kk = 0; kk < 4; ++kk) {
        b0[kk] = *(const sx8*)(WaT + col0 * K3 + 128 + kk * 32 + q * 8);
        b1[kk] = *(const sx8*)(WaT + col1 * K3 + 128 + kk * 32 + q * 8);
    }
    __syncthreads();   // B1: A0 staged

    // ---- GEMM1: [48x128] over hE (reads bufA) ----
    fx4 acc[3][2];
#pragma unroll
    for (int mt = 0; mt < 3; ++mt)
#pragma unroll
        for (int nt = 0; nt < 2; ++nt)
#pragma unroll
            for (int r = 0; r < 4; ++r) acc[mt][nt][r] = 0.0f;
#pragma unroll
    for (int kk = 0; kk < 4; ++kk) {
#pragma unroll
        for (int mt = 0; mt < 3; ++mt) {
            sx8 af = *(const sx8*)(A0 + (mt * 16 + m16) * 136 + kk * 32 + q * 8);
            acc[mt][0] = __builtin_amdgcn_mfma_f32_16x16x32_bf16(af, b0[kk], acc[mt][0], 0, 0, 0);
            acc[mt][1] = __builtin_amdgcn_mfma_f32_16x16x32_bf16(af, b1[kk], acc[mt][1], 0, 0, 0);
        }
    }

    // ---- prefetch GEMM2 B-frags ----
    sx8 p0[4], p1[4];
#pragma unroll
    for (int kk = 0; kk < 4; ++kk) {
        p0[kk] = *(const sx8*)(WbT + col0 * CC + kk * 32 + q * 8);
        p1[kk] = *(const sx8*)(WbT + col1 * CC + kk * 32 + q * 8);
    }

    // ---- epilogue 1: acc + Pc + Pn -> gelu -> X1 (bufB fresh; no barrier) --
#pragma unroll
    for (int mt = 0; mt < 3; ++mt)
#pragma unroll
        for (int r = 0; r < 4; ++r) {
            int row = mt * 16 + q * 4 + r;
            X1[row * 136 + col0] = f2bs(gelu_f(acc[mt][0][r] + pc0 + pn0[mt][r]));
            X1[row * 136 + col1] = f2bs(gelu_f(acc[mt][1][r] + pc1 + pn1[mt][r]));
        }
    __syncthreads();   // B2: X1 ready (also: all waves past GEMM1)

    // ---- GEMM2: [48x128] @ WbT' (reads bufB) ----
    fx4 acc2[3][2];
#pragma unroll
    for (int mt = 0; mt < 3; ++mt)
#pragma unroll
        for (int nt = 0; nt < 2; ++nt)
#pragma unroll
            for (int r = 0; r < 4; ++r) acc2[mt][nt][r] = 0.0f;
#pragma unroll
    for (int kk = 0; kk < 4; ++kk) {
#pragma unroll
        for (int mt = 0; mt < 3; ++mt) {
            sx8 af = *(const sx8*)(X1 + (mt * 16 + m16) * 136 + kk * 32 + q * 8);
            acc2[mt][0] = __builtin_amdgcn_mfma_f32_16x16x32_bf16(af, p0[kk], acc2[mt][0], 0, 0, 0);
            acc2[mt][1] = __builtin_amdgcn_mfma_f32_16x16x32_bf16(af, p1[kk], acc2[mt][1], 0, 0, 0);
        }
    }

    // ---- prefetch GEMM3 B-frags + pass-specific operands ----
    sx8 t0[4], t1[4];
#pragma unroll
    for (int kk = 0; kk < 4; ++kk) {
        t0[kk] = *(const sx8*)(WcT + col0 * CC + kk * 32 + q * 8);
        t1[kk] = *(const sx8*)(WcT + col1 * CC + kk * 32 + q * 8);
    }
    float mrow[12];
    float res0[12], res1[12];
    if constexpr (PASS == 1) {
#pragma unroll
        for (int mt = 0; mt < 3; ++mt)
#pragma unroll
            for (int r = 0; r < 4; ++r)
                mrow[mt * 4 + r] = mask_att[bn * KE + mt * 16 + q * 4 + r];
    } else {
#pragma unroll
        for (int mt = 0; mt < 3; ++mt)
#pragma unroll
            for (int r = 0; r < 4; ++r) {
                int row = mt * 16 + q * 4 + r;
                res0[mt * 4 + r] = hE[((size_t)bn * KE + row) * CC + col0];
                res1[mt * 4 + r] = hE[((size_t)bn * KE + row) * CC + col1];
            }
    }

    // ---- epilogue 2: gelu -> X2 (bufA; safe: B2 proved all past GEMM1) ----
    {
        float bb0 = Wbb[col0], bb1 = Wbb[col1];
#pragma unroll
        for (int mt = 0; mt < 3; ++mt)
#pragma unroll
            for (int r = 0; r < 4; ++r) {
                int row = mt * 16 + q * 4 + r;
                A0[row * 136 + col0] = f2bs(gelu_f(acc2[mt][0][r] + bb0));
                A0[row * 136 + col1] = f2bs(gelu_f(acc2[mt][1][r] + bb1));
            }
    }
    __syncthreads();   // B3: X2 ready (also: all waves past GEMM2)

    // ---- GEMM3: [48x128] @ WcT' (reads bufA) ----
    fx4 acc3[3][2];
#pragma unroll
    for (int mt = 0; mt < 3; ++mt)
#pragma unroll
        for (int nt = 0; nt < 2; ++nt)
#pragma unroll
            for (int r = 0; r < 4; ++r) acc3[mt][nt][r] = 0.0f;
#pragma unroll
    for (int kk = 0; kk < 4; ++kk) {
#pragma unroll
        for (int mt = 0; mt < 3; ++mt) {
            sx8 af = *(const sx8*)(A0 + (mt * 16 + m16) * 136 + kk * 32 + q * 8);
            acc3[mt][0] = __builtin_amdgcn_mfma_f32_16x16x32_bf16(af, t0[kk], acc3[mt][0], 0, 0, 0);
            acc3[mt][1] = __builtin_amdgcn_mfma_f32_16x16x32_bf16(af, t1[kk], acc3[mt][1], 0, 0, 0);
        }
    }

    float bc0 = Wcb[col0], bc1 = Wcb[col1];

    if constexpr (PASS == 1) {
        // masked sum over the 48 edge rows -> dh[col]
        float ps0 = 0.f, ps1 = 0.f;
#pragma unroll
        for (int mt = 0; mt < 3; ++mt)
#pragma unroll
            for (int r = 0; r < 4; ++r) {
                float m = mrow[mt * 4 + r];
                ps0 += m * (acc3[mt][0][r] + bc0);
                ps1 += m * (acc3[mt][1][r] + bc1);
            }
        // dhp aliases bufB (X1): safe, B3 proved all waves past GEMM2
        dhp[q * 128 + col0] = ps0;
        dhp[q * 128 + col1] = ps1;
        __syncthreads();   // B4
        float val = 0.f;
        if (tid < 128) {
            float dh = dhp[tid] + dhp[128 + tid] + dhp[256 + tid] + dhp[384 + tid];
            val = hVsrc[(size_t)bn * CC + tid] + dh * (1.0f / 30.0f);
            float sv1 = val, sv2 = val * val;
#pragma unroll
            for (int m = 32; m >= 1; m >>= 1) {
                sv1 += __shfl_xor(sv1, m);
                sv2 += __shfl_xor(sv2, m);
            }
            if ((tid & 63) == 0) {
                redp[(tid >> 6) * 2]     = sv1;
                redp[(tid >> 6) * 2 + 1] = sv2;
            }
        }
        __syncthreads();   // B5
        if (tid < 128) {
            float mean = (redp[0] + redp[2]) * (1.0f / 128.0f);
            float var  = (redp[1] + redp[3]) * (1.0f / 128.0f) - mean * mean;
            float rstd = rsqrtf(fmaxf(var, 0.0f) + 1e-5f);
            hv1_out[(size_t)bn * CC + tid] = gamma[tid] * (val - mean) * rstd + beta[tid];
        }
    } else {
        __syncthreads();   // B4: all waves done reading bufA (S spans both)
        // S = hE + msg (fp32, LDS -- R7 lesson: registers can't hold this)
#pragma unroll
        for (int mt = 0; mt < 3; ++mt)
#pragma unroll
            for (int r = 0; r < 4; ++r) {
                int row = mt * 16 + q * 4 + r;
                S[row * 132 + col0] = res0[mt * 4 + r] + acc3[mt][0][r] + bc0;
                S[row * 132 + col1] = res1[mt * 4 + r] + acc3[mt][1][r] + bc1;
            }
        __syncthreads();   // B5
        // per-edge-row LayerNorm; 8 groups of 32 lanes, 6 rows each
        int g = tid >> 5, l32 = tid & 31;
        for (int r = g; r < 48; r += 8) {
            float x0 = S[r * 132 + l32];
            float x1 = S[r * 132 + l32 + 32];
            float x2 = S[r * 132 + l32 + 64];
            float x3 = S[r * 132 + l32 + 96];
            float sv1 = x0 + x1 + x2 + x3;
            float sv2 = x0 * x0 + x1 * x1 + x2 * x2 + x3 * x3;
#pragma unroll
            for (int m = 16; m >= 1; m >>= 1) {
                sv1 += __shfl_xor(sv1, m, 32);
                sv2 += __shfl_xor(sv2, m, 32);
            }
            float mean = sv1 * (1.0f / 128.0f);
            float var  = sv2 * (1.0f / 128.0f) - mean * mean;
            float rstd = rsqrtf(fmaxf(var, 0.0f) + 1e-5f);
            float* orow = hE_out + ((size_t)bn * KE + r) * CC;
            orow[l32]      = gamma[l32] * (x0 - mean) * rstd + beta[l32];
            orow[l32 + 32] = gamma[l32 + 32] * (x1 - mean) * rstd + beta[l32 + 32];
            orow[l32 + 64] = gamma[l32 + 64] * (x2 - mean) * rstd + beta[l32 + 64];
            orow[l32 + 96] = gamma[l32 + 96] * (x3 - mean) * rstd + beta[l32 + 96];
        }
    }
}

// ---------------------------------------------------------------------------
// MFMA FFN + fused pass-2 node projections -- R12: 512 threads (8 waves),
// 16 nodes/block, grid 256. Old version was 4 waves = 1 wave/SIMD: ZERO
// latency hiding. Now 2 waves/SIMD, per-wave tiles halved:
//   GEMM1: wave w -> hidden cols [64w,64w+64) (4 ntiles, 16 B-frags)
//   GEMM2: wave w -> out col 16w+m16 (1 ntile, 16 B-frags)
//   LN2:   16 groups x 32 lanes, single pass
//   P-tail: wave w -> Pc/Pn col 16w+m16 (8 B-frags)
// ---------------------------------------------------------------------------
__global__ __launch_bounds__(512, 2) void ffn_kernel(
    float* __restrict__ hv, const short* __restrict__ WinT,
    const float* __restrict__ Winb, const short* __restrict__ WoutT,
    const float* __restrict__ Woutb, const float* __restrict__ g2,
    const float* __restrict__ b2, const float* __restrict__ maskV,
    const short* __restrict__ W11T, const float* __restrict__ b11,
    float* __restrict__ Pc, float* __restrict__ Pn) {
    __shared__ __align__(16) float hvF[16 * 132];   // fp32 residual / LN buffer
    __shared__ __align__(16) short Abf[16 * 136];   // bf16 A (GEMM1, then P)
    __shared__ __align__(16) short Xs[16 * 520];    // bf16 hidden for GEMM2

    const int tid = threadIdx.x;
    const int bn  = blockIdx.x;       // node tile: nodes [bn*16, bn*16+16)
    const int wave = tid >> 6, lane = tid & 63, q = lane >> 4, m16 = lane & 15;
    const int col = wave * 16 + m16;  // GEMM2 / P-tail column

    // ---- prefetch GEMM1 B-frags (this wave's 64 cols x K=128) ----
    sx8 bw[4][4];
#pragma unroll
    for (int kk = 0; kk < 4; ++kk)
#pragma unroll
        for (int nt = 0; nt < 4; ++nt)
            bw[kk][nt] = *(const sx8*)(WinT + (wave * 64 + nt * 16 + m16) * CC + kk * 32 + q * 8);

    // ---- stage hv tile: fp32 copy + bf16 copy (1 chunk/thread) ----
    {
        int row = tid >> 5;                          // 32 chunks/row
        int c4  = (tid & 31) * 4;
        float4 v = *(const float4*)(hv + (bn * 16 + row) * CC + c4);
        hvF[row * 132 + c4]     = v.x;
        hvF[row * 132 + c4 + 1] = v.y;
        hvF[row * 132 + c4 + 2] = v.z;
        hvF[row * 132 + c4 + 3] = v.w;
        Abf[row * 136 + c4]     = f2bs(v.x);
        Abf[row * 136 + c4 + 1] = f2bs(v.y);
        Abf[row * 136 + c4 + 2] = f2bs(v.z);
        Abf[row * 136 + c4 + 3] = f2bs(v.w);
    }
    __syncthreads();

    // ---- GEMM1: hidden cols [64w, 64w+64) (B all in registers) ----
    fx4 acc1[4];
#pragma unroll
    for (int nt = 0; nt < 4; ++nt)
#pragma unroll
        for (int r = 0; r < 4; ++r) acc1[nt][r] = 0.0f;
#pragma unroll
    for (int kk = 0; kk < 4; ++kk) {
        sx8 af = *(const sx8*)(Abf + m16 * 136 + kk * 32 + q * 8);
#pragma unroll
        for (int nt = 0; nt < 4; ++nt)
            acc1[nt] = __builtin_amdgcn_mfma_f32_16x16x32_bf16(af, bw[kk][nt], acc1[nt], 0, 0, 0);
    }

    // ---- prefetch GEMM2 B-frags (overlap epilogue + barrier) ----
    sx8 c0a[16];
#pragma unroll
    for (int kk = 0; kk < 16; ++kk)
        c0a[kk] = *(const sx8*)(WoutT + col * FFD + kk * 32 + q * 8);

#pragma unroll
    for (int nt = 0; nt < 4; ++nt) {
        int coln = wave * 64 + nt * 16 + m16;
        float bi = Winb[coln];
#pragma unroll
        for (int r = 0; r < 4; ++r) {
            int row = q * 4 + r;
            Xs[row * 520 + coln] = f2bs(gelu_f(acc1[nt][r] + bi));
        }
    }
    __syncthreads();

    // ---- GEMM2: out col (wave*16+m16) (B all in registers) ----
    fx4 o0;
#pragma unroll
    for (int r = 0; r < 4; ++r) o0[r] = 0.0f;
#pragma unroll
    for (int kk = 0; kk < 16; ++kk) {
        sx8 af = *(const sx8*)(Xs + m16 * 520 + kk * 32 + q * 8);
        o0 = __builtin_amdgcn_mfma_f32_16x16x32_bf16(af, c0a[kk], o0, 0, 0, 0);
    }
    {
        float bo = Woutb[col];
#pragma unroll
        for (int r = 0; r < 4; ++r)
            hvF[(q * 4 + r) * 132 + col] += o0[r] + bo;
    }
    __syncthreads();

    // ---- per-node LN2 + mask (16 groups x 32 lanes, single pass) ----
    {
        int g = tid >> 5, l32 = tid & 31;
        int row = g;
        float x0 = hvF[row * 132 + l32];
        float x1 = hvF[row * 132 + l32 + 32];
        float x2 = hvF[row * 132 + l32 + 64];
        float x3 = hvF[row * 132 + l32 + 96];
        float s1 = x0 + x1 + x2 + x3;
        float s2 = x0 * x0 + x1 * x1 + x2 * x2 + x3 * x3;
#pragma unroll
        for (int m = 16; m >= 1; m >>= 1) {
            s1 += __shfl_xor(s1, m, 32);
            s2 += __shfl_xor(s2, m, 32);
        }
        float mean = s1 * (1.0f / 128.0f);
        float var  = s2 * (1.0f / 128.0f) - mean * mean;
        float rstd = rsqrtf(fmaxf(var, 0.0f) + 1e-5f);
        int node = bn * 16 + row;
        float mk = maskV[node];
        float* orow = hv + node * CC;
        float y0 = mk * (g2[l32] * (x0 - mean) * rstd + b2[l32]);
        float y1 = mk * (g2[l32 + 32] * (x1 - mean) * rstd + b2[l32 + 32]);
        float y2 = mk * (g2[l32 + 64] * (x2 - mean) * rstd + b2[l32 + 64]);
        float y3 = mk * (g2[l32 + 96] * (x3 - mean) * rstd + b2[l32 + 96]);
        orow[l32]      = y0;
        orow[l32 + 32] = y1;
        orow[l32 + 64] = y2;
        orow[l32 + 96] = y3;
        Abf[row * 136 + l32]      = f2bs(y0);
        Abf[row * 136 + l32 + 32] = f2bs(y1);
        Abf[row * 136 + l32 + 64] = f2bs(y2);
        Abf[row * 136 + l32 + 96] = f2bs(y3);
    }
    __syncthreads();   // Abf = final hv tile (bf16)

    // ---- fused pass-2 precompute: Pc/Pn col (wave*16+m16) ----
    {
        fx4 pcA, pnA;
#pragma unroll
        for (int r = 0; r < 4; ++r) { pcA[r] = 0.f; pnA[r] = 0.f; }
#pragma unroll
        for (int kk = 0; kk < 4; ++kk) {
            sx8 af  = *(const sx8*)(Abf + m16 * 136 + kk * 32 + q * 8);
            sx8 bc  = *(const sx8*)(W11T + col * K3 + kk * 32 + q * 8);
            sx8 bns = *(const sx8*)(W11T + col * K3 + 256 + kk * 32 + q * 8);
            pcA = __builtin_amdgcn_mfma_f32_16x16x32_bf16(af, bc, pcA, 0, 0, 0);
            pnA = __builtin_amdgcn_mfma_f32_16x16x32_bf16(af, bns, pnA, 0, 0, 0);
        }
        float bi = b11[col];
#pragma unroll
        for (int r = 0; r < 4; ++r) {
            int node = bn * 16 + q * 4 + r;
            Pc[(size_t)node * CC + col] = pcA[r] + bi;
            Pn[(size_t)node * CC + col] = pnA[r];
        }
    }
}

extern "C" void kernel_launch(void* const* d_in, const int* in_sizes, int n_in,
                              void* d_out, int out_size, void* d_ws, size_t ws_size,
                              hipStream_t stream) {
    (void)in_sizes; (void)n_in; (void)out_size; (void)ws_size;
    const float* hV    = (const float*)d_in[0];
    const float* hE    = (const float*)d_in[1];
    const int*   Eidx  = (const int*)d_in[2];
    const float* maskV = (const float*)d_in[3];
    const float* maskA = (const float*)d_in[4];
    const float* W1w  = (const float*)d_in[5];
    const float* W1b  = (const float*)d_in[6];
    const float* W2w  = (const float*)d_in[7];
    const float* W2b  = (const float*)d_in[8];
    const float* W3w  = (const float*)d_in[9];
    const float* W3b  = (const float*)d_in[10];
    const float* W11w = (const float*)d_in[11];
    const float* W11b = (const float*)d_in[12];
    const float* W12w = (const float*)d_in[13];
    const float* W12b = (const float*)d_in[14];
    const float* W13w = (const float*)d_in[15];
    const float* W13b = (const float*)d_in[16];
    const float* Winw = (const float*)d_in[17];
    const float* Winb = (const float*)d_in[18];
    const float* Woutw = (const float*)d_in[19];
    const float* Woutb = (const float*)d_in[20];
    const float* g1 = (const float*)d_in[21];
    const float* b1 = (const float*)d_in[22];
    const float* g2 = (const float*)d_in[23];
    const float* b2 = (const float*)d_in[24];
    const float* g3 = (const float*)d_in[25];
    const float* b3 = (const float*)d_in[26];

    short* wt   = (short*)d_ws;                    // 294912 bf16 = 576KB
    float* Pc   = (float*)((char*)d_ws + 589824);  // [4096,128] fp32 = 2MB
    float* Pn   = Pc + (size_t)BB * NN * CC;       // [4096,128] fp32 = 2MB
    float* outV = (float*)d_out;                   // h_V region [4096,128]
    float* outE = outV + (size_t)BB * NN * CC;     // h_E region [4096,48,128]

    prep_weights<<<1152, 256, 0, stream>>>(W1w, W2w, W3w, W11w, W12w, W13w, Winw, Woutw, wt);
    precompute_P<<<256, 256, 0, stream>>>(hV, wt, W1b, Pc, Pn);
    edge_pass<1><<<BB * NN, 256, 0, stream>>>(hV, hE, Eidx,
                                              wt, wt + 49152, W2b, wt + 65536, W3b,
                                              Pc, Pn, maskA, outV, g1, b1, nullptr);
    ffn_kernel<<<256, 512, 0, stream>>>(outV, wt + 163840, Winb, wt + 229376, Woutb, g2, b2, maskV,
                                        wt + 81920, W11b, Pc, Pn);
    edge_pass<2><<<BB * NN, 256, 0, stream>>>(outV, hE, Eidx,
                                              wt + 81920, wt + 131072, W12b, wt + 147456, W13b,
                                              Pc, Pn, nullptr, nullptr, g3, b3, outE);
}

// Round 10
// 340.073 us; speedup vs baseline: 1.1389x; 1.1389x over previous
//
#include <hip/hip_runtime.h>
#include <hip/hip_bf16.h>

// Problem constants (fixed by the reference)
#define BB 2
#define NN 2048
#define KE 48     // neighbors per node
#define CC 128
#define FFD 512
#define K3 384    // 3*C (full weight row stride in WT layout)

// bf16 MFMA fragment types (guide §3, HW-verified m89/m91/m92)
typedef short sx8 __attribute__((ext_vector_type(8)));   // 8 bf16 in 4 VGPRs
typedef float fx4 __attribute__((ext_vector_type(4)));   // 4 fp32 acc

__device__ __forceinline__ short f2bs(float f) {
    __bf16 h = (__bf16)f;            // RNE fp32->bf16
    return __builtin_bit_cast(short, h);
}

// Fast exact-quality GELU: erf via Abramowitz-Stegun 7.1.26, |err|<1.5e-7.
__device__ __forceinline__ float gelu_f(float x) {
    float z = fabsf(x) * 0.70710678118654752f;
    float e = __expf(-z * z);
    float t = __builtin_amdgcn_rcpf(fmaf(0.3275911f, z, 1.0f));
    float poly = t * fmaf(t, fmaf(t, fmaf(t, fmaf(t, 1.061405429f, -1.453152027f),
                                          1.421413741f), -0.284496736f), 0.254829592f);
    float erf = 1.0f - poly * e;
    float phi = fmaf(copysignf(erf, x), 0.5f, 0.5f);
    return x * phi;
}

// load 8 consecutive fp32 (32B aligned) and convert to bf16x8 (as short8)
__device__ __forceinline__ sx8 cvt8f(const float* p) {
    float4 a = *(const float4*)p;
    float4 b = *(const float4*)(p + 4);
    sx8 r;
    r[0] = f2bs(a.x); r[1] = f2bs(a.y); r[2] = f2bs(a.z); r[3] = f2bs(a.w);
    r[4] = f2bs(b.x); r[5] = f2bs(b.y); r[6] = f2bs(b.z); r[7] = f2bs(b.w);
    return r;
}

// pack two float4 (already in registers) to bf16x8
__device__ __forceinline__ sx8 pack8(float4 a, float4 b) {
    sx8 r;
    r[0] = f2bs(a.x); r[1] = f2bs(a.y); r[2] = f2bs(a.z); r[3] = f2bs(a.w);
    r[4] = f2bs(b.x); r[5] = f2bs(b.y); r[6] = f2bs(b.z); r[7] = f2bs(b.w);
    return r;
}

// ---------------------------------------------------------------------------
// Transpose + fp32->bf16 convert the 8 weight matrices into ws (unchanged).
// bf16-elem offsets: W1T@0(128x384) W2T@49152(128x128) W3T@65536
// W11T@81920(128x384) W12T@131072 W13T@147456 WinT@163840(512x128)
// WoutT@229376(128x512); total 294912 elems (576KB); Pc/Pn fp32 follow.
// ---------------------------------------------------------------------------
__global__ void prep_weights(const float* __restrict__ W1, const float* __restrict__ W2,
                             const float* __restrict__ W3, const float* __restrict__ W11,
                             const float* __restrict__ W12, const float* __restrict__ W13,
                             const float* __restrict__ Win, const float* __restrict__ Wout,
                             short* __restrict__ wt) {
    int i = blockIdx.x * 256 + threadIdx.x;  // grid covers exactly 294912
    const float* src;
    short* dst;
    int R, S, local;   // R = inner (k) extent of WT; S = row stride of source
    if (i < 49152)       { src = W1;   dst = wt;          R = 384; S = 128; local = i; }
    else if (i < 65536)  { src = W2;   dst = wt + 49152;  R = 128; S = 128; local = i - 49152; }
    else if (i < 81920)  { src = W3;   dst = wt + 65536;  R = 128; S = 128; local = i - 65536; }
    else if (i < 131072) { src = W11;  dst = wt + 81920;  R = 384; S = 128; local = i - 81920; }
    else if (i < 147456) { src = W12;  dst = wt + 131072; R = 128; S = 128; local = i - 131072; }
    else if (i < 163840) { src = W13;  dst = wt + 147456; R = 128; S = 128; local = i - 147456; }
    else if (i < 229376) { src = Win;  dst = wt + 163840; R = 128; S = 512; local = i - 163840; }
    else                 { src = Wout; dst = wt + 229376; R = 512; S = 128; local = i - 229376; }
    int c = local / R;
    int r = local - c * R;
    dst[local] = f2bs(src[r * S + c]);  // WT[c][r] = W[r][c]
}

// ---------------------------------------------------------------------------
// Precompute node projections for edge pass 1:
//   Pc[n][c] = hv[n] @ W[0:128][c]   + bias[c]     (ctr part of concat, +b)
//   Pn[n][c] = hv[n] @ W[256:384][c]               (nbr part of concat)
// 16 nodes per block, grid 256; wave w covers cols [32w, 32w+32) for both.
// (Pass-2's instance is fused into the tail of ffn_kernel.)
// ---------------------------------------------------------------------------
__global__ __launch_bounds__(256) void precompute_P(
    const float* __restrict__ hv, const short* __restrict__ WT,
    const float* __restrict__ bias, float* __restrict__ Pc,
    float* __restrict__ Pn) {
    __shared__ __align__(16) short Abf[16 * 136];
    const int tid = threadIdx.x;
    const int bn  = blockIdx.x;       // node tile [bn*16, bn*16+16)
    const int wave = tid >> 6, lane = tid & 63, q = lane >> 4, m16 = lane & 15;
    const int col0 = wave * 32 + m16, col1 = col0 + 16;

    {   // stage 16x128 A-tile as bf16: one sx8 per thread
        int row = tid >> 4, seg = tid & 15;
        *(sx8*)(Abf + row * 136 + seg * 8) = cvt8f(hv + (size_t)(bn * 16 + row) * CC + seg * 8);
    }
    __syncthreads();

    fx4 c0, c1, n0, n1;
#pragma unroll
    for (int r = 0; r < 4; ++r) { c0[r] = 0.f; c1[r] = 0.f; n0[r] = 0.f; n1[r] = 0.f; }
#pragma unroll
    for (int kk = 0; kk < 4; ++kk) {
        sx8 af = *(const sx8*)(Abf + m16 * 136 + kk * 32 + q * 8);
        sx8 bc0 = *(const sx8*)(WT + col0 * K3 + kk * 32 + q * 8);
        sx8 bc1 = *(const sx8*)(WT + col1 * K3 + kk * 32 + q * 8);
        sx8 bn0 = *(const sx8*)(WT + col0 * K3 + 256 + kk * 32 + q * 8);
        sx8 bn1 = *(const sx8*)(WT + col1 * K3 + 256 + kk * 32 + q * 8);
        c0 = __builtin_amdgcn_mfma_f32_16x16x32_bf16(af, bc0, c0, 0, 0, 0);
        c1 = __builtin_amdgcn_mfma_f32_16x16x32_bf16(af, bc1, c1, 0, 0, 0);
        n0 = __builtin_amdgcn_mfma_f32_16x16x32_bf16(af, bn0, n0, 0, 0, 0);
        n1 = __builtin_amdgcn_mfma_f32_16x16x32_bf16(af, bn1, n1, 0, 0, 0);
    }
    float bi0 = bias[col0], bi1 = bias[col1];
#pragma unroll
    for (int r = 0; r < 4; ++r) {
        int node = bn * 16 + q * 4 + r;
        Pc[(size_t)node * CC + col0] = c0[r] + bi0;
        Pc[(size_t)node * CC + col1] = c1[r] + bi1;
        Pn[(size_t)node * CC + col0] = n0[r];
        Pn[(size_t)node * CC + col1] = n1[r];
    }
}

// ---------------------------------------------------------------------------
// Edge MLP pass -- R13: byte-identical to R8's proven 90us kernel at
// __launch_bounds__(256,5). OCCUPANCY LEVER CLOSED: (256,6) spilled three
// times (R2/R6/R9 -- WRITE_SIZE inflation + VGPR collapse) even though the
// (256,5) build reports VGPR=48; the allocator's pre-regalloc pressure is
// >85 and any cap <=85 forces wholesale scratch.
//   bufA @0 (13056B): hE bf16 tile (GEMM1 A) -> X2 (GEMM3 A).
//   bufB @13056 (13056B): X1 (GEMM2 A) -> dhp/redp (PASS1).
//   S (PASS2, 48x132 fp32 = 25344B) spans both buffers; written post-B4.
// Barriers: 5 both passes.
// ---------------------------------------------------------------------------
template <int PASS>
__global__ __launch_bounds__(256, 5) void edge_pass(
    const float* __restrict__ hVsrc, const float* __restrict__ hE,
    const int* __restrict__ Eidx,
    const short* __restrict__ WaT,
    const short* __restrict__ WbT, const float* __restrict__ Wbb,
    const short* __restrict__ WcT, const float* __restrict__ Wcb,
    const float* __restrict__ Pc, const float* __restrict__ Pn,
    const float* __restrict__ mask_att, float* __restrict__ hv1_out,
    const float* __restrict__ gamma, const float* __restrict__ beta,
    float* __restrict__ hE_out) {
    __shared__ __align__(16) unsigned char smem_raw[26112];
    short* A0   = (short*)smem_raw;                    // bufA: hE tile -> X2
    short* X1   = (short*)(smem_raw + 13056);          // bufB: X1 -> scratch
    float* S    = (float*)smem_raw;                    // PASS2 LN (spans both)
    float* dhp  = (float*)(smem_raw + 13056);          // PASS1: 512 floats
    float* redp = (float*)(smem_raw + 13056 + 2048);   // PASS1: 4 floats

    const int tid = threadIdx.x;
    const int bn  = blockIdx.x;       // b*N+n
    const int bb  = bn >> 11;         // batch (N=2048)
    const int wave = tid >> 6, lane = tid & 63, q = lane >> 4, m16 = lane & 15;
    const int col0 = wave * 32 + m16; // ntile 2*wave
    const int col1 = col0 + 16;       // ntile 2*wave+1
    const int r0 = tid >> 4, seg = tid & 15;

    // ---- Eidx for this lane's 12 acc rows (row = mt*16 + q*4 + r) ----
    int e[3][4];
#pragma unroll
    for (int mt = 0; mt < 3; ++mt)
#pragma unroll
        for (int r = 0; r < 4; ++r)
            e[mt][r] = Eidx[bn * KE + mt * 16 + q * 4 + r];

    // ---- Pc / Pn gathers: issued now, consumed at epilogue 1 ----
    float pc0 = Pc[(size_t)bn * CC + col0];
    float pc1 = Pc[(size_t)bn * CC + col1];
    float pn0[3][4], pn1[3][4];
#pragma unroll
    for (int mt = 0; mt < 3; ++mt)
#pragma unroll
        for (int r = 0; r < 4; ++r) {
            size_t prow = ((size_t)bb * NN + e[mt][r]) * CC;
            pn0[mt][r] = Pn[prow + col0];
            pn1[mt][r] = Pn[prow + col1];
        }

    // ---- stage A0 = hE tile (3 rows/thread, 6 float4 loads batched) ----
    {
        const float* he = hE + (size_t)bn * KE * CC + seg * 8;
        float4 h0a = *(const float4*)(he + r0 * CC);
        float4 h0b = *(const float4*)(he + r0 * CC + 4);
        float4 h1a = *(const float4*)(he + (r0 + 16) * CC);
        float4 h1b = *(const float4*)(he + (r0 + 16) * CC + 4);
        float4 h2a = *(const float4*)(he + (r0 + 32) * CC);
        float4 h2b = *(const float4*)(he + (r0 + 32) * CC + 4);
        *(sx8*)(A0 + r0 * 136 + seg * 8)        = pack8(h0a, h0b);
        *(sx8*)(A0 + (r0 + 16) * 136 + seg * 8) = pack8(h1a, h1b);
        *(sx8*)(A0 + (r0 + 32) * 136 + seg * 8) = pack8(h2a, h2b);
    }

    // ---- prefetch GEMM1 B-frags: W1 rows 128..255 (hE block) ----
    sx8 b0[4], b1[4];
#pragma unroll
    for (int kk = 0; kk < 4; ++kk) {
        b0[kk] = *(const sx8*)(WaT + col0 * K3 + 128 + kk * 32 + q * 8);
        b1[kk] = *(const sx8*)(WaT + col1 * K3 + 128 + kk * 32 + q * 8);
    }
    __syncthreads();   // B1: A0 staged

    // ---- GEMM1: [48x128] over hE (reads bufA) ----
    fx4 acc[3][2];
#pragma unroll
    for (int mt = 0; mt < 3; ++mt)
#pragma unroll
        for (int nt = 0; nt < 2; ++nt)
#pragma unroll
            for (int r = 0; r < 4; ++r) acc[mt][nt][r] = 0.0f;
#pragma unroll
    for (int kk = 0; kk < 4; ++kk) {
#pragma unroll
        for (int mt = 0; mt < 3; ++mt) {
            sx8 af = *(const sx8*)(A0 + (mt * 16 + m16) * 136 + kk * 32 + q * 8);
            acc[mt][0] = __builtin_amdgcn_mfma_f32_16x16x32_bf16(af, b0[kk], acc[mt][0], 0, 0, 0);
            acc[mt][1] = __builtin_amdgcn_mfma_f32_16x16x32_bf16(af, b1[kk], acc[mt][1], 0, 0, 0);
        }
    }

    // ---- prefetch GEMM2 B-frags ----
    sx8 p0[4], p1[4];
#pragma unroll
    for (int kk = 0; kk < 4; ++kk) {
        p0[kk] = *(const sx8*)(WbT + col0 * CC + kk * 32 + q * 8);
        p1[kk] = *(const sx8*)(WbT + col1 * CC + kk * 32 + q * 8);
    }

    // ---- epilogue 1: acc + Pc + Pn -> gelu -> X1 (bufB fresh; no barrier) --
#pragma unroll
    for (int mt = 0; mt < 3; ++mt)
#pragma unroll
        for (int r = 0; r < 4; ++r) {
            int row = mt * 16 + q * 4 + r;
            X1[row * 136 + col0] = f2bs(gelu_f(acc[mt][0][r] + pc0 + pn0[mt][r]));
            X1[row * 136 + col1] = f2bs(gelu_f(acc[mt][1][r] + pc1 + pn1[mt][r]));
        }
    __syncthreads();   // B2: X1 ready (also: all waves past GEMM1)

    // ---- GEMM2: [48x128] @ WbT' (reads bufB) ----
    fx4 acc2[3][2];
#pragma unroll
    for (int mt = 0; mt < 3; ++mt)
#pragma unroll
        for (int nt = 0; nt < 2; ++nt)
#pragma unroll
            for (int r = 0; r < 4; ++r) acc2[mt][nt][r] = 0.0f;
#pragma unroll
    for (int kk = 0; kk < 4; ++kk) {
#pragma unroll
        for (int mt = 0; mt < 3; ++mt) {
            sx8 af = *(const sx8*)(X1 + (mt * 16 + m16) * 136 + kk * 32 + q * 8);
            acc2[mt][0] = __builtin_amdgcn_mfma_f32_16x16x32_bf16(af, p0[kk], acc2[mt][0], 0, 0, 0);
            acc2[mt][1] = __builtin_amdgcn_mfma_f32_16x16x32_bf16(af, p1[kk], acc2[mt][1], 0, 0, 0);
        }
    }

    // ---- prefetch GEMM3 B-frags + pass-specific operands ----
    sx8 t0[4], t1[4];
#pragma unroll
    for (int kk = 0; kk < 4; ++kk) {
        t0[kk] = *(const sx8*)(WcT + col0 * CC + kk * 32 + q * 8);
        t1[kk] = *(const sx8*)(WcT + col1 * CC + kk * 32 + q * 8);
    }
    float mrow[12];
    float res0[12], res1[12];
    if constexpr (PASS == 1) {
#pragma unroll
        for (int mt = 0; mt < 3; ++mt)
#pragma unroll
            for (int r = 0; r < 4; ++r)
                mrow[mt * 4 + r] = mask_att[bn * KE + mt * 16 + q * 4 + r];
    } else {
#pragma unroll
        for (int mt = 0; mt < 3; ++mt)
#pragma unroll
            for (int r = 0; r < 4; ++r) {
                int row = mt * 16 + q * 4 + r;
                res0[mt * 4 + r] = hE[((size_t)bn * KE + row) * CC + col0];
                res1[mt * 4 + r] = hE[((size_t)bn * KE + row) * CC + col1];
            }
    }

    // ---- epilogue 2: gelu -> X2 (bufA; safe: B2 proved all past GEMM1) ----
    {
        float bb0 = Wbb[col0], bb1 = Wbb[col1];
#pragma unroll
        for (int mt = 0; mt < 3; ++mt)
#pragma unroll
            for (int r = 0; r < 4; ++r) {
                int row = mt * 16 + q * 4 + r;
                A0[row * 136 + col0] = f2bs(gelu_f(acc2[mt][0][r] + bb0));
                A0[row * 136 + col1] = f2bs(gelu_f(acc2[mt][1][r] + bb1));
            }
    }
    __syncthreads();   // B3: X2 ready (also: all waves past GEMM2)

    // ---- GEMM3: [48x128] @ WcT' (reads bufA) ----
    fx4 acc3[3][2];
#pragma unroll
    for (int mt = 0; mt < 3; ++mt)
#pragma unroll
        for (int nt = 0; nt < 2; ++nt)
#pragma unroll
            for (int r = 0; r < 4; ++r) acc3[mt][nt][r] = 0.0f;
#pragma unroll
    for (int kk = 0; kk < 4; ++kk) {
#pragma unroll
        for (int mt = 0; mt < 3; ++mt) {
            sx8 af = *(const sx8*)(A0 + (mt * 16 + m16) * 136 + kk * 32 + q * 8);
            acc3[mt][0] = __builtin_amdgcn_mfma_f32_16x16x32_bf16(af, t0[kk], acc3[mt][0], 0, 0, 0);
            acc3[mt][1] = __builtin_amdgcn_mfma_f32_16x16x32_bf16(af, t1[kk], acc3[mt][1], 0, 0, 0);
        }
    }

    float bc0 = Wcb[col0], bc1 = Wcb[col1];

    if constexpr (PASS == 1) {
        // masked sum over the 48 edge rows -> dh[col]
        float ps0 = 0.f, ps1 = 0.f;
#pragma unroll
        for (int mt = 0; mt < 3; ++mt)
#pragma unroll
            for (int r = 0; r < 4; ++r) {
                float m = mrow[mt * 4 + r];
                ps0 += m * (acc3[mt][0][r] + bc0);
                ps1 += m * (acc3[mt][1][r] + bc1);
            }
        // dhp aliases bufB (X1): safe, B3 proved all waves past GEMM2
        dhp[q * 128 + col0] = ps0;
        dhp[q * 128 + col1] = ps1;
        __syncthreads();   // B4
        float val = 0.f;
        if (tid < 128) {
            float dh = dhp[tid] + dhp[128 + tid] + dhp[256 + tid] + dhp[384 + tid];
            val = hVsrc[(size_t)bn * CC + tid] + dh * (1.0f / 30.0f);
            float sv1 = val, sv2 = val * val;
#pragma unroll
            for (int m = 32; m >= 1; m >>= 1) {
                sv1 += __shfl_xor(sv1, m);
                sv2 += __shfl_xor(sv2, m);
            }
            if ((tid & 63) == 0) {
                redp[(tid >> 6) * 2]     = sv1;
                redp[(tid >> 6) * 2 + 1] = sv2;
            }
        }
        __syncthreads();   // B5
        if (tid < 128) {
            float mean = (redp[0] + redp[2]) * (1.0f / 128.0f);
            float var  = (redp[1] + redp[3]) * (1.0f / 128.0f) - mean * mean;
            float rstd = rsqrtf(fmaxf(var, 0.0f) + 1e-5f);
            hv1_out[(size_t)bn * CC + tid] = gamma[tid] * (val - mean) * rstd + beta[tid];
        }
    } else {
        __syncthreads();   // B4: all waves done reading bufA (S spans both)
        // S = hE + msg (fp32, LDS -- R7 lesson: registers can't hold this)
#pragma unroll
        for (int mt = 0; mt < 3; ++mt)
#pragma unroll
            for (int r = 0; r < 4; ++r) {
                int row = mt * 16 + q * 4 + r;
                S[row * 132 + col0] = res0[mt * 4 + r] + acc3[mt][0][r] + bc0;
                S[row * 132 + col1] = res1[mt * 4 + r] + acc3[mt][1][r] + bc1;
            }
        __syncthreads();   // B5
        // per-edge-row LayerNorm; 8 groups of 32 lanes, 6 rows each
        int g = tid >> 5, l32 = tid & 31;
        for (int r = g; r < 48; r += 8) {
            float x0 = S[r * 132 + l32];
            float x1 = S[r * 132 + l32 + 32];
            float x2 = S[r * 132 + l32 + 64];
            float x3 = S[r * 132 + l32 + 96];
            float sv1 = x0 + x1 + x2 + x3;
            float sv2 = x0 * x0 + x1 * x1 + x2 * x2 + x3 * x3;
#pragma unroll
            for (int m = 16; m >= 1; m >>= 1) {
                sv1 += __shfl_xor(sv1, m, 32);
                sv2 += __shfl_xor(sv2, m, 32);
            }
            float mean = sv1 * (1.0f / 128.0f);
            float var  = sv2 * (1.0f / 128.0f) - mean * mean;
            float rstd = rsqrtf(fmaxf(var, 0.0f) + 1e-5f);
            float* orow = hE_out + ((size_t)bn * KE + r) * CC;
            orow[l32]      = gamma[l32] * (x0 - mean) * rstd + beta[l32];
            orow[l32 + 32] = gamma[l32 + 32] * (x1 - mean) * rstd + beta[l32 + 32];
            orow[l32 + 64] = gamma[l32 + 64] * (x2 - mean) * rstd + beta[l32 + 64];
            orow[l32 + 96] = gamma[l32 + 96] * (x3 - mean) * rstd + beta[l32 + 96];
        }
    }
}

// ---------------------------------------------------------------------------
// MFMA FFN + fused pass-2 node projections -- 512 threads (8 waves),
// 16 nodes/block, grid 256 -> 2 waves/SIMD (was 1: zero latency hiding).
//   GEMM1: wave w -> hidden cols [64w,64w+64) (4 ntiles, 16 B-frags)
//   GEMM2: wave w -> out col 16w+m16 (1 ntile, 16 B-frags)
//   LN2:   16 groups x 32 lanes, single pass
//   P-tail: wave w -> Pc/Pn col 16w+m16 (8 B-frags)
// ---------------------------------------------------------------------------
__global__ __launch_bounds__(512, 2) void ffn_kernel(
    float* __restrict__ hv, const short* __restrict__ WinT,
    const float* __restrict__ Winb, const short* __restrict__ WoutT,
    const float* __restrict__ Woutb, const float* __restrict__ g2,
    const float* __restrict__ b2, const float* __restrict__ maskV,
    const short* __restrict__ W11T, const float* __restrict__ b11,
    float* __restrict__ Pc, float* __restrict__ Pn) {
    __shared__ __align__(16) float hvF[16 * 132];   // fp32 residual / LN buffer
    __shared__ __align__(16) short Abf[16 * 136];   // bf16 A (GEMM1, then P)
    __shared__ __align__(16) short Xs[16 * 520];    // bf16 hidden for GEMM2

    const int tid = threadIdx.x;
    const int bn  = blockIdx.x;       // node tile: nodes [bn*16, bn*16+16)
    const int wave = tid >> 6, lane = tid & 63, q = lane >> 4, m16 = lane & 15;
    const int col = wave * 16 + m16;  // GEMM2 / P-tail column

    // ---- prefetch GEMM1 B-frags (this wave's 64 cols x K=128) ----
    sx8 bw[4][4];
#pragma unroll
    for (int kk = 0; kk < 4; ++kk)
#pragma unroll
        for (int nt = 0; nt < 4; ++nt)
            bw[kk][nt] = *(const sx8*)(WinT + (wave * 64 + nt * 16 + m16) * CC + kk * 32 + q * 8);

    // ---- stage hv tile: fp32 copy + bf16 copy (1 chunk/thread) ----
    {
        int row = tid >> 5;                          // 32 chunks/row
        int c4  = (tid & 31) * 4;
        float4 v = *(const float4*)(hv + (bn * 16 + row) * CC + c4);
        hvF[row * 132 + c4]     = v.x;
        hvF[row * 132 + c4 + 1] = v.y;
        hvF[row * 132 + c4 + 2] = v.z;
        hvF[row * 132 + c4 + 3] = v.w;
        Abf[row * 136 + c4]     = f2bs(v.x);
        Abf[row * 136 + c4 + 1] = f2bs(v.y);
        Abf[row * 136 + c4 + 2] = f2bs(v.z);
        Abf[row * 136 + c4 + 3] = f2bs(v.w);
    }
    __syncthreads();

    // ---- GEMM1: hidden cols [64w, 64w+64) (B all in registers) ----
    fx4 acc1[4];
#pragma unroll
    for (int nt = 0; nt < 4; ++nt)
#pragma unroll
        for (int r = 0; r < 4; ++r) acc1[nt][r] = 0.0f;
#pragma unroll
    for (int kk = 0; kk < 4; ++kk) {
        sx8 af = *(const sx8*)(Abf + m16 * 136 + kk * 32 + q * 8);
#pragma unroll
        for (int nt = 0; nt < 4; ++nt)
            acc1[nt] = __builtin_amdgcn_mfma_f32_16x16x32_bf16(af, bw[kk][nt], acc1[nt], 0, 0, 0);
    }

    // ---- prefetch GEMM2 B-frags (overlap epilogue + barrier) ----
    sx8 c0a[16];
#pragma unroll
    for (int kk = 0; kk < 16; ++kk)
        c0a[kk] = *(const sx8*)(WoutT + col * FFD + kk * 32 + q * 8);

#pragma unroll
    for (int nt = 0; nt < 4; ++nt) {
        int coln = wave * 64 + nt * 16 + m16;
        float bi = Winb[coln];
#pragma unroll
        for (int r = 0; r < 4; ++r) {
            int row = q * 4 + r;
            Xs[row * 520 + coln] = f2bs(gelu_f(acc1[nt][r] + bi));
        }
    }
    __syncthreads();

    // ---- GEMM2: out col (wave*16+m16) (B all in registers) ----
    fx4 o0;
#pragma unroll
    for (int r = 0; r < 4; ++r) o0[r] = 0.0f;
#pragma unroll
    for (int kk = 0; kk < 16; ++kk) {
        sx8 af = *(const sx8*)(Xs + m16 * 520 + kk * 32 + q * 8);
        o0 = __builtin_amdgcn_mfma_f32_16x16x32_bf16(af, c0a[kk], o0, 0, 0, 0);
    }
    {
        float bo = Woutb[col];
#pragma unroll
        for (int r = 0; r < 4; ++r)
            hvF[(q * 4 + r) * 132 + col] += o0[r] + bo;
    }
    __syncthreads();

    // ---- per-node LN2 + mask (16 groups x 32 lanes, single pass) ----
    {
        int g = tid >> 5, l32 = tid & 31;
        int row = g;
        float x0 = hvF[row * 132 + l32];
        float x1 = hvF[row * 132 + l32 + 32];
        float x2 = hvF[row * 132 + l32 + 64];
        float x3 = hvF[row * 132 + l32 + 96];
        float s1 = x0 + x1 + x2 + x3;
        float s2 = x0 * x0 + x1 * x1 + x2 * x2 + x3 * x3;
#pragma unroll
        for (int m = 16; m >= 1; m >>= 1) {
            s1 += __shfl_xor(s1, m, 32);
            s2 += __shfl_xor(s2, m, 32);
        }
        float mean = s1 * (1.0f / 128.0f);
        float var  = s2 * (1.0f / 128.0f) - mean * mean;
        float rstd = rsqrtf(fmaxf(var, 0.0f) + 1e-5f);
        int node = bn * 16 + row;
        float mk = maskV[node];
        float* orow = hv + node * CC;
        float y0 = mk * (g2[l32] * (x0 - mean) * rstd + b2[l32]);
        float y1 = mk * (g2[l32 + 32] * (x1 - mean) * rstd + b2[l32 + 32]);
        float y2 = mk * (g2[l32 + 64] * (x2 - mean) * rstd + b2[l32 + 64]);
        float y3 = mk * (g2[l32 + 96] * (x3 - mean) * rstd + b2[l32 + 96]);
        orow[l32]      = y0;
        orow[l32 + 32] = y1;
        orow[l32 + 64] = y2;
        orow[l32 + 96] = y3;
        Abf[row * 136 + l32]      = f2bs(y0);
        Abf[row * 136 + l32 + 32] = f2bs(y1);
        Abf[row * 136 + l32 + 64] = f2bs(y2);
        Abf[row * 136 + l32 + 96] = f2bs(y3);
    }
    __syncthreads();   // Abf = final hv tile (bf16)

    // ---- fused pass-2 precompute: Pc/Pn col (wave*16+m16) ----
    {
        fx4 pcA, pnA;
#pragma unroll
        for (int r = 0; r < 4; ++r) { pcA[r] = 0.f; pnA[r] = 0.f; }
#pragma unroll
        for (int kk = 0; kk < 4; ++kk) {
            sx8 af  = *(const sx8*)(Abf + m16 * 136 + kk * 32 + q * 8);
            sx8 bc  = *(const sx8*)(W11T + col * K3 + kk * 32 + q * 8);
            sx8 bns = *(const sx8*)(W11T + col * K3 + 256 + kk * 32 + q * 8);
            pcA = __builtin_amdgcn_mfma_f32_16x16x32_bf16(af, bc, pcA, 0, 0, 0);
            pnA = __builtin_amdgcn_mfma_f32_16x16x32_bf16(af, bns, pnA, 0, 0, 0);
        }
        float bi = b11[col];
#pragma unroll
        for (int r = 0; r < 4; ++r) {
            int node = bn * 16 + q * 4 + r;
            Pc[(size_t)node * CC + col] = pcA[r] + bi;
            Pn[(size_t)node * CC + col] = pnA[r];
        }
    }
}

extern "C" void kernel_launch(void* const* d_in, const int* in_sizes, int n_in,
                              void* d_out, int out_size, void* d_ws, size_t ws_size,
                              hipStream_t stream) {
    (void)in_sizes; (void)n_in; (void)out_size; (void)ws_size;
    const float* hV    = (const float*)d_in[0];
    const float* hE    = (const float*)d_in[1];
    const int*   Eidx  = (const int*)d_in[2];
    const float* maskV = (const float*)d_in[3];
    const float* maskA = (const float*)d_in[4];
    const float* W1w  = (const float*)d_in[5];
    const float* W1b  = (const float*)d_in[6];
    const float* W2w  = (const float*)d_in[7];
    const float* W2b  = (const float*)d_in[8];
    const float* W3w  = (const float*)d_in[9];
    const float* W3b  = (const float*)d_in[10];
    const float* W11w = (const float*)d_in[11];
    const float* W11b = (const float*)d_in[12];
    const float* W12w = (const float*)d_in[13];
    const float* W12b = (const float*)d_in[14];
    const float* W13w = (const float*)d_in[15];
    const float* W13b = (const float*)d_in[16];
    const float* Winw = (const float*)d_in[17];
    const float* Winb = (const float*)d_in[18];
    const float* Woutw = (const float*)d_in[19];
    const float* Woutb = (const float*)d_in[20];
    const float* g1 = (const float*)d_in[21];
    const float* b1 = (const float*)d_in[22];
    const float* g2 = (const float*)d_in[23];
    const float* b2 = (const float*)d_in[24];
    const float* g3 = (const float*)d_in[25];
    const float* b3 = (const float*)d_in[26];

    short* wt   = (short*)d_ws;                    // 294912 bf16 = 576KB
    float* Pc   = (float*)((char*)d_ws + 589824);  // [4096,128] fp32 = 2MB
    float* Pn   = Pc + (size_t)BB * NN * CC;       // [4096,128] fp32 = 2MB
    float* outV = (float*)d_out;                   // h_V region [4096,128]
    float* outE = outV + (size_t)BB * NN * CC;     // h_E region [4096,48,128]

    prep_weights<<<1152, 256, 0, stream>>>(W1w, W2w, W3w, W11w, W12w, W13w, Winw, Woutw, wt);
    precompute_P<<<256, 256, 0, stream>>>(hV, wt, W1b, Pc, Pn);
    edge_pass<1><<<BB * NN, 256, 0, stream>>>(hV, hE, Eidx,
                                              wt, wt + 49152, W2b, wt + 65536, W3b,
                                              Pc, Pn, maskA, outV, g1, b1, nullptr);
    ffn_kernel<<<256, 512, 0, stream>>>(outV, wt + 163840, Winb, wt + 229376, Woutb, g2, b2, maskV,
                                        wt + 81920, W11b, Pc, Pn);
    edge_pass<2><<<BB * NN, 256, 0, stream>>>(outV, hE, Eidx,
                                              wt + 81920, wt + 131072, W12b, wt + 147456, W13b,
                                              Pc, Pn, nullptr, nullptr, g3, b3, outE);
}

// Round 11
// 335.782 us; speedup vs baseline: 1.1535x; 1.0128x over previous
//
#include <hip/hip_runtime.h>
#include <hip/hip_bf16.h>

// Problem constants (fixed by the reference)
#define BB 2
#define NN 2048
#define KE 48     // neighbors per node
#define CC 128
#define FFD 512
#define K3 384    // 3*C (full weight row stride in WT layout)

// bf16 MFMA fragment types (guide §3, HW-verified m89/m91/m92)
typedef short sx8 __attribute__((ext_vector_type(8)));   // 8 bf16 in 4 VGPRs
typedef float fx4 __attribute__((ext_vector_type(4)));   // 4 fp32 acc

__device__ __forceinline__ short f2bs(float f) {
    __bf16 h = (__bf16)f;            // RNE fp32->bf16
    return __builtin_bit_cast(short, h);
}

// Fast exact-quality GELU: erf via Abramowitz-Stegun 7.1.26, |err|<1.5e-7.
__device__ __forceinline__ float gelu_f(float x) {
    float z = fabsf(x) * 0.70710678118654752f;
    float e = __expf(-z * z);
    float t = __builtin_amdgcn_rcpf(fmaf(0.3275911f, z, 1.0f));
    float poly = t * fmaf(t, fmaf(t, fmaf(t, fmaf(t, 1.061405429f, -1.453152027f),
                                          1.421413741f), -0.284496736f), 0.254829592f);
    float erf = 1.0f - poly * e;
    float phi = fmaf(copysignf(erf, x), 0.5f, 0.5f);
    return x * phi;
}

// load 8 consecutive fp32 (32B aligned) and convert to bf16x8 (as short8)
__device__ __forceinline__ sx8 cvt8f(const float* p) {
    float4 a = *(const float4*)p;
    float4 b = *(const float4*)(p + 4);
    sx8 r;
    r[0] = f2bs(a.x); r[1] = f2bs(a.y); r[2] = f2bs(a.z); r[3] = f2bs(a.w);
    r[4] = f2bs(b.x); r[5] = f2bs(b.y); r[6] = f2bs(b.z); r[7] = f2bs(b.w);
    return r;
}

// pack two float4 (already in registers) to bf16x8
__device__ __forceinline__ sx8 pack8(float4 a, float4 b) {
    sx8 r;
    r[0] = f2bs(a.x); r[1] = f2bs(a.y); r[2] = f2bs(a.z); r[3] = f2bs(a.w);
    r[4] = f2bs(b.x); r[5] = f2bs(b.y); r[6] = f2bs(b.z); r[7] = f2bs(b.w);
    return r;
}

// ---------------------------------------------------------------------------
// prep_weights R14: LDS tile transpose, coalesced on BOTH sides (old version
// read src at 512B stride -- 64-lane scatter). 72 blocks, one 64x64 tile
// each; all matrix dims are multiples of 64.
// Tile table (dst bf16-elem offsets unchanged): W1T@0(128x384, 12 tiles)
// W2T@49152(4) W3T@65536(4) W11T@81920(12) W12T@131072(4) W13T@147456(4)
// WinT@163840(512x128, 16) WoutT@229376(128x512, 16). Total 72 tiles.
// ---------------------------------------------------------------------------
__global__ __launch_bounds__(256) void prep_weights(
    const float* __restrict__ W1, const float* __restrict__ W2,
    const float* __restrict__ W3, const float* __restrict__ W11,
    const float* __restrict__ W12, const float* __restrict__ W13,
    const float* __restrict__ Win, const float* __restrict__ Wout,
    short* __restrict__ wt) {
    __shared__ short T[64][72];   // stride 72 shorts = 144B (16B-aligned rows)

    int b = blockIdx.x;
    const float* src; short* dst; int Rr, Ss, tloc;
    if (b < 12)      { src = W1;   dst = wt;          Rr = 384; Ss = 128; tloc = b; }
    else if (b < 16) { src = W2;   dst = wt + 49152;  Rr = 128; Ss = 128; tloc = b - 12; }
    else if (b < 20) { src = W3;   dst = wt + 65536;  Rr = 128; Ss = 128; tloc = b - 16; }
    else if (b < 32) { src = W11;  dst = wt + 81920;  Rr = 384; Ss = 128; tloc = b - 20; }
    else if (b < 36) { src = W12;  dst = wt + 131072; Rr = 128; Ss = 128; tloc = b - 32; }
    else if (b < 40) { src = W13;  dst = wt + 147456; Rr = 128; Ss = 128; tloc = b - 36; }
    else if (b < 56) { src = Win;  dst = wt + 163840; Rr = 128; Ss = 512; tloc = b - 40; }
    else             { src = Wout; dst = wt + 229376; Rr = 512; Ss = 128; tloc = b - 56; }
    int ntr = Rr >> 6;                 // tiles along r
    int tr = tloc % ntr, tc = tloc / ntr;

    const int t = threadIdx.x;
    // ---- load: 4 coalesced float4 rows per thread-group, cvt -> T[c][r] ----
    {
        int lr  = t >> 4;              // 0..15
        int lc4 = (t & 15) * 4;        // 0..60
#pragma unroll
        for (int rr = 0; rr < 4; ++rr) {
            int r = tr * 64 + lr + rr * 16;
            int c = tc * 64 + lc4;
            float4 v = *(const float4*)(src + (size_t)r * Ss + c);
            int rl = lr + rr * 16;
            T[lc4 + 0][rl] = f2bs(v.x);
            T[lc4 + 1][rl] = f2bs(v.y);
            T[lc4 + 2][rl] = f2bs(v.z);
            T[lc4 + 3][rl] = f2bs(v.w);
        }
    }
    __syncthreads();
    // ---- store: thread -> (c-row, 16-short chunk); 128B contiguous/quad ----
    {
        int cl  = t >> 2;              // 0..63
        int rch = (t & 3) * 16;        // 0,16,32,48
        short* drow = dst + (size_t)(tc * 64 + cl) * Rr + tr * 64 + rch;
        *(sx8*)(drow)     = *(const sx8*)(&T[cl][rch]);
        *(sx8*)(drow + 8) = *(const sx8*)(&T[cl][rch + 8]);
    }
}

// ---------------------------------------------------------------------------
// Precompute node projections for edge pass 1:
//   Pc[n][c] = hv[n] @ W[0:128][c]   + bias[c]     (ctr part of concat, +b)
//   Pn[n][c] = hv[n] @ W[256:384][c]               (nbr part of concat)
// 16 nodes per block, grid 256; wave w covers cols [32w, 32w+32) for both.
// (Pass-2's instance is fused into the tail of ffn_kernel.)
// ---------------------------------------------------------------------------
__global__ __launch_bounds__(256) void precompute_P(
    const float* __restrict__ hv, const short* __restrict__ WT,
    const float* __restrict__ bias, float* __restrict__ Pc,
    float* __restrict__ Pn) {
    __shared__ __align__(16) short Abf[16 * 136];
    const int tid = threadIdx.x;
    const int bn  = blockIdx.x;       // node tile [bn*16, bn*16+16)
    const int wave = tid >> 6, lane = tid & 63, q = lane >> 4, m16 = lane & 15;
    const int col0 = wave * 32 + m16, col1 = col0 + 16;

    {   // stage 16x128 A-tile as bf16: one sx8 per thread
        int row = tid >> 4, seg = tid & 15;
        *(sx8*)(Abf + row * 136 + seg * 8) = cvt8f(hv + (size_t)(bn * 16 + row) * CC + seg * 8);
    }
    __syncthreads();

    fx4 c0, c1, n0, n1;
#pragma unroll
    for (int r = 0; r < 4; ++r) { c0[r] = 0.f; c1[r] = 0.f; n0[r] = 0.f; n1[r] = 0.f; }
#pragma unroll
    for (int kk = 0; kk < 4; ++kk) {
        sx8 af = *(const sx8*)(Abf + m16 * 136 + kk * 32 + q * 8);
        sx8 bc0 = *(const sx8*)(WT + col0 * K3 + kk * 32 + q * 8);
        sx8 bc1 = *(const sx8*)(WT + col1 * K3 + kk * 32 + q * 8);
        sx8 bn0 = *(const sx8*)(WT + col0 * K3 + 256 + kk * 32 + q * 8);
        sx8 bn1 = *(const sx8*)(WT + col1 * K3 + 256 + kk * 32 + q * 8);
        c0 = __builtin_amdgcn_mfma_f32_16x16x32_bf16(af, bc0, c0, 0, 0, 0);
        c1 = __builtin_amdgcn_mfma_f32_16x16x32_bf16(af, bc1, c1, 0, 0, 0);
        n0 = __builtin_amdgcn_mfma_f32_16x16x32_bf16(af, bn0, n0, 0, 0, 0);
        n1 = __builtin_amdgcn_mfma_f32_16x16x32_bf16(af, bn1, n1, 0, 0, 0);
    }
    float bi0 = bias[col0], bi1 = bias[col1];
#pragma unroll
    for (int r = 0; r < 4; ++r) {
        int node = bn * 16 + q * 4 + r;
        Pc[(size_t)node * CC + col0] = c0[r] + bi0;
        Pc[(size_t)node * CC + col1] = c1[r] + bi1;
        Pn[(size_t)node * CC + col0] = n0[r];
        Pn[(size_t)node * CC + col1] = n1[r];
    }
}

// ---------------------------------------------------------------------------
// Edge MLP pass -- byte-identical to R8/R10's proven kernel at (256,5).
// OCCUPANCY LEVER CLOSED: (256,6) spilled three times (R2/R6/R9).
//   bufA @0 (13056B): hE bf16 tile (GEMM1 A) -> X2 (GEMM3 A).
//   bufB @13056 (13056B): X1 (GEMM2 A) -> dhp/redp (PASS1).
//   S (PASS2, 48x132 fp32 = 25344B) spans both buffers; written post-B4.
// Barriers: 5 both passes.
// ---------------------------------------------------------------------------
template <int PASS>
__global__ __launch_bounds__(256, 5) void edge_pass(
    const float* __restrict__ hVsrc, const float* __restrict__ hE,
    const int* __restrict__ Eidx,
    const short* __restrict__ WaT,
    const short* __restrict__ WbT, const float* __restrict__ Wbb,
    const short* __restrict__ WcT, const float* __restrict__ Wcb,
    const float* __restrict__ Pc, const float* __restrict__ Pn,
    const float* __restrict__ mask_att, float* __restrict__ hv1_out,
    const float* __restrict__ gamma, const float* __restrict__ beta,
    float* __restrict__ hE_out) {
    __shared__ __align__(16) unsigned char smem_raw[26112];
    short* A0   = (short*)smem_raw;                    // bufA: hE tile -> X2
    short* X1   = (short*)(smem_raw + 13056);          // bufB: X1 -> scratch
    float* S    = (float*)smem_raw;                    // PASS2 LN (spans both)
    float* dhp  = (float*)(smem_raw + 13056);          // PASS1: 512 floats
    float* redp = (float*)(smem_raw + 13056 + 2048);   // PASS1: 4 floats

    const int tid = threadIdx.x;
    const int bn  = blockIdx.x;       // b*N+n
    const int bb  = bn >> 11;         // batch (N=2048)
    const int wave = tid >> 6, lane = tid & 63, q = lane >> 4, m16 = lane & 15;
    const int col0 = wave * 32 + m16; // ntile 2*wave
    const int col1 = col0 + 16;       // ntile 2*wave+1
    const int r0 = tid >> 4, seg = tid & 15;

    // ---- Eidx for this lane's 12 acc rows (row = mt*16 + q*4 + r) ----
    int e[3][4];
#pragma unroll
    for (int mt = 0; mt < 3; ++mt)
#pragma unroll
        for (int r = 0; r < 4; ++r)
            e[mt][r] = Eidx[bn * KE + mt * 16 + q * 4 + r];

    // ---- Pc / Pn gathers: issued now, consumed at epilogue 1 ----
    float pc0 = Pc[(size_t)bn * CC + col0];
    float pc1 = Pc[(size_t)bn * CC + col1];
    float pn0[3][4], pn1[3][4];
#pragma unroll
    for (int mt = 0; mt < 3; ++mt)
#pragma unroll
        for (int r = 0; r < 4; ++r) {
            size_t prow = ((size_t)bb * NN + e[mt][r]) * CC;
            pn0[mt][r] = Pn[prow + col0];
            pn1[mt][r] = Pn[prow + col1];
        }

    // ---- stage A0 = hE tile (3 rows/thread, 6 float4 loads batched) ----
    {
        const float* he = hE + (size_t)bn * KE * CC + seg * 8;
        float4 h0a = *(const float4*)(he + r0 * CC);
        float4 h0b = *(const float4*)(he + r0 * CC + 4);
        float4 h1a = *(const float4*)(he + (r0 + 16) * CC);
        float4 h1b = *(const float4*)(he + (r0 + 16) * CC + 4);
        float4 h2a = *(const float4*)(he + (r0 + 32) * CC);
        float4 h2b = *(const float4*)(he + (r0 + 32) * CC + 4);
        *(sx8*)(A0 + r0 * 136 + seg * 8)        = pack8(h0a, h0b);
        *(sx8*)(A0 + (r0 + 16) * 136 + seg * 8) = pack8(h1a, h1b);
        *(sx8*)(A0 + (r0 + 32) * 136 + seg * 8) = pack8(h2a, h2b);
    }

    // ---- prefetch GEMM1 B-frags: W1 rows 128..255 (hE block) ----
    sx8 b0[4], b1[4];
#pragma unroll
    for (int kk = 0; kk < 4; ++kk) {
        b0[kk] = *(const sx8*)(WaT + col0 * K3 + 128 + kk * 32 + q * 8);
        b1[kk] = *(const sx8*)(WaT + col1 * K3 + 128 + kk * 32 + q * 8);
    }
    __syncthreads();   // B1: A0 staged

    // ---- GEMM1: [48x128] over hE (reads bufA) ----
    fx4 acc[3][2];
#pragma unroll
    for (int mt = 0; mt < 3; ++mt)
#pragma unroll
        for (int nt = 0; nt < 2; ++nt)
#pragma unroll
            for (int r = 0; r < 4; ++r) acc[mt][nt][r] = 0.0f;
#pragma unroll
    for (int kk = 0; kk < 4; ++kk) {
#pragma unroll
        for (int mt = 0; mt < 3; ++mt) {
            sx8 af = *(const sx8*)(A0 + (mt * 16 + m16) * 136 + kk * 32 + q * 8);
            acc[mt][0] = __builtin_amdgcn_mfma_f32_16x16x32_bf16(af, b0[kk], acc[mt][0], 0, 0, 0);
            acc[mt][1] = __builtin_amdgcn_mfma_f32_16x16x32_bf16(af, b1[kk], acc[mt][1], 0, 0, 0);
        }
    }

    // ---- prefetch GEMM2 B-frags ----
    sx8 p0[4], p1[4];
#pragma unroll
    for (int kk = 0; kk < 4; ++kk) {
        p0[kk] = *(const sx8*)(WbT + col0 * CC + kk * 32 + q * 8);
        p1[kk] = *(const sx8*)(WbT + col1 * CC + kk * 32 + q * 8);
    }

    // ---- epilogue 1: acc + Pc + Pn -> gelu -> X1 (bufB fresh; no barrier) --
#pragma unroll
    for (int mt = 0; mt < 3; ++mt)
#pragma unroll
        for (int r = 0; r < 4; ++r) {
            int row = mt * 16 + q * 4 + r;
            X1[row * 136 + col0] = f2bs(gelu_f(acc[mt][0][r] + pc0 + pn0[mt][r]));
            X1[row * 136 + col1] = f2bs(gelu_f(acc[mt][1][r] + pc1 + pn1[mt][r]));
        }
    __syncthreads();   // B2: X1 ready (also: all waves past GEMM1)

    // ---- GEMM2: [48x128] @ WbT' (reads bufB) ----
    fx4 acc2[3][2];
#pragma unroll
    for (int mt = 0; mt < 3; ++mt)
#pragma unroll
        for (int nt = 0; nt < 2; ++nt)
#pragma unroll
            for (int r = 0; r < 4; ++r) acc2[mt][nt][r] = 0.0f;
#pragma unroll
    for (int kk = 0; kk < 4; ++kk) {
#pragma unroll
        for (int mt = 0; mt < 3; ++mt) {
            sx8 af = *(const sx8*)(X1 + (mt * 16 + m16) * 136 + kk * 32 + q * 8);
            acc2[mt][0] = __builtin_amdgcn_mfma_f32_16x16x32_bf16(af, p0[kk], acc2[mt][0], 0, 0, 0);
            acc2[mt][1] = __builtin_amdgcn_mfma_f32_16x16x32_bf16(af, p1[kk], acc2[mt][1], 0, 0, 0);
        }
    }

    // ---- prefetch GEMM3 B-frags + pass-specific operands ----
    sx8 t0[4], t1[4];
#pragma unroll
    for (int kk = 0; kk < 4; ++kk) {
        t0[kk] = *(const sx8*)(WcT + col0 * CC + kk * 32 + q * 8);
        t1[kk] = *(const sx8*)(WcT + col1 * CC + kk * 32 + q * 8);
    }
    float mrow[12];
    float res0[12], res1[12];
    if constexpr (PASS == 1) {
#pragma unroll
        for (int mt = 0; mt < 3; ++mt)
#pragma unroll
            for (int r = 0; r < 4; ++r)
                mrow[mt * 4 + r] = mask_att[bn * KE + mt * 16 + q * 4 + r];
    } else {
#pragma unroll
        for (int mt = 0; mt < 3; ++mt)
#pragma unroll
            for (int r = 0; r < 4; ++r) {
                int row = mt * 16 + q * 4 + r;
                res0[mt * 4 + r] = hE[((size_t)bn * KE + row) * CC + col0];
                res1[mt * 4 + r] = hE[((size_t)bn * KE + row) * CC + col1];
            }
    }

    // ---- epilogue 2: gelu -> X2 (bufA; safe: B2 proved all past GEMM1) ----
    {
        float bb0 = Wbb[col0], bb1 = Wbb[col1];
#pragma unroll
        for (int mt = 0; mt < 3; ++mt)
#pragma unroll
            for (int r = 0; r < 4; ++r) {
                int row = mt * 16 + q * 4 + r;
                A0[row * 136 + col0] = f2bs(gelu_f(acc2[mt][0][r] + bb0));
                A0[row * 136 + col1] = f2bs(gelu_f(acc2[mt][1][r] + bb1));
            }
    }
    __syncthreads();   // B3: X2 ready (also: all waves past GEMM2)

    // ---- GEMM3: [48x128] @ WcT' (reads bufA) ----
    fx4 acc3[3][2];
#pragma unroll
    for (int mt = 0; mt < 3; ++mt)
#pragma unroll
        for (int nt = 0; nt < 2; ++nt)
#pragma unroll
            for (int r = 0; r < 4; ++r) acc3[mt][nt][r] = 0.0f;
#pragma unroll
    for (int kk = 0; kk < 4; ++kk) {
#pragma unroll
        for (int mt = 0; mt < 3; ++mt) {
            sx8 af = *(const sx8*)(A0 + (mt * 16 + m16) * 136 + kk * 32 + q * 8);
            acc3[mt][0] = __builtin_amdgcn_mfma_f32_16x16x32_bf16(af, t0[kk], acc3[mt][0], 0, 0, 0);
            acc3[mt][1] = __builtin_amdgcn_mfma_f32_16x16x32_bf16(af, t1[kk], acc3[mt][1], 0, 0, 0);
        }
    }

    float bc0 = Wcb[col0], bc1 = Wcb[col1];

    if constexpr (PASS == 1) {
        // masked sum over the 48 edge rows -> dh[col]
        float ps0 = 0.f, ps1 = 0.f;
#pragma unroll
        for (int mt = 0; mt < 3; ++mt)
#pragma unroll
            for (int r = 0; r < 4; ++r) {
                float m = mrow[mt * 4 + r];
                ps0 += m * (acc3[mt][0][r] + bc0);
                ps1 += m * (acc3[mt][1][r] + bc1);
            }
        // dhp aliases bufB (X1): safe, B3 proved all waves past GEMM2
        dhp[q * 128 + col0] = ps0;
        dhp[q * 128 + col1] = ps1;
        __syncthreads();   // B4
        float val = 0.f;
        if (tid < 128) {
            float dh = dhp[tid] + dhp[128 + tid] + dhp[256 + tid] + dhp[384 + tid];
            val = hVsrc[(size_t)bn * CC + tid] + dh * (1.0f / 30.0f);
            float sv1 = val, sv2 = val * val;
#pragma unroll
            for (int m = 32; m >= 1; m >>= 1) {
                sv1 += __shfl_xor(sv1, m);
                sv2 += __shfl_xor(sv2, m);
            }
            if ((tid & 63) == 0) {
                redp[(tid >> 6) * 2]     = sv1;
                redp[(tid >> 6) * 2 + 1] = sv2;
            }
        }
        __syncthreads();   // B5
        if (tid < 128) {
            float mean = (redp[0] + redp[2]) * (1.0f / 128.0f);
            float var  = (redp[1] + redp[3]) * (1.0f / 128.0f) - mean * mean;
            float rstd = rsqrtf(fmaxf(var, 0.0f) + 1e-5f);
            hv1_out[(size_t)bn * CC + tid] = gamma[tid] * (val - mean) * rstd + beta[tid];
        }
    } else {
        __syncthreads();   // B4: all waves done reading bufA (S spans both)
        // S = hE + msg (fp32, LDS -- R7 lesson: registers can't hold this)
#pragma unroll
        for (int mt = 0; mt < 3; ++mt)
#pragma unroll
            for (int r = 0; r < 4; ++r) {
                int row = mt * 16 + q * 4 + r;
                S[row * 132 + col0] = res0[mt * 4 + r] + acc3[mt][0][r] + bc0;
                S[row * 132 + col1] = res1[mt * 4 + r] + acc3[mt][1][r] + bc1;
            }
        __syncthreads();   // B5
        // per-edge-row LayerNorm; 8 groups of 32 lanes, 6 rows each
        int g = tid >> 5, l32 = tid & 31;
        for (int r = g; r < 48; r += 8) {
            float x0 = S[r * 132 + l32];
            float x1 = S[r * 132 + l32 + 32];
            float x2 = S[r * 132 + l32 + 64];
            float x3 = S[r * 132 + l32 + 96];
            float sv1 = x0 + x1 + x2 + x3;
            float sv2 = x0 * x0 + x1 * x1 + x2 * x2 + x3 * x3;
#pragma unroll
            for (int m = 16; m >= 1; m >>= 1) {
                sv1 += __shfl_xor(sv1, m, 32);
                sv2 += __shfl_xor(sv2, m, 32);
            }
            float mean = sv1 * (1.0f / 128.0f);
            float var  = sv2 * (1.0f / 128.0f) - mean * mean;
            float rstd = rsqrtf(fmaxf(var, 0.0f) + 1e-5f);
            float* orow = hE_out + ((size_t)bn * KE + r) * CC;
            orow[l32]      = gamma[l32] * (x0 - mean) * rstd + beta[l32];
            orow[l32 + 32] = gamma[l32 + 32] * (x1 - mean) * rstd + beta[l32 + 32];
            orow[l32 + 64] = gamma[l32 + 64] * (x2 - mean) * rstd + beta[l32 + 64];
            orow[l32 + 96] = gamma[l32 + 96] * (x3 - mean) * rstd + beta[l32 + 96];
        }
    }
}

// ---------------------------------------------------------------------------
// MFMA FFN + fused pass-2 node projections -- 512 threads (8 waves),
// 16 nodes/block, grid 256 -> 2 waves/SIMD.
//   GEMM1: wave w -> hidden cols [64w,64w+64) (4 ntiles, 16 B-frags)
//   GEMM2: wave w -> out col 16w+m16 (1 ntile, 16 B-frags)
//   LN2:   16 groups x 32 lanes, single pass
//   P-tail: wave w -> Pc/Pn col 16w+m16 (8 B-frags)
// ---------------------------------------------------------------------------
__global__ __launch_bounds__(512, 2) void ffn_kernel(
    float* __restrict__ hv, const short* __restrict__ WinT,
    const float* __restrict__ Winb, const short* __restrict__ WoutT,
    const float* __restrict__ Woutb, const float* __restrict__ g2,
    const float* __restrict__ b2, const float* __restrict__ maskV,
    const short* __restrict__ W11T, const float* __restrict__ b11,
    float* __restrict__ Pc, float* __restrict__ Pn) {
    __shared__ __align__(16) float hvF[16 * 132];   // fp32 residual / LN buffer
    __shared__ __align__(16) short Abf[16 * 136];   // bf16 A (GEMM1, then P)
    __shared__ __align__(16) short Xs[16 * 520];    // bf16 hidden for GEMM2

    const int tid = threadIdx.x;
    const int bn  = blockIdx.x;       // node tile: nodes [bn*16, bn*16+16)
    const int wave = tid >> 6, lane = tid & 63, q = lane >> 4, m16 = lane & 15;
    const int col = wave * 16 + m16;  // GEMM2 / P-tail column

    // ---- prefetch GEMM1 B-frags (this wave's 64 cols x K=128) ----
    sx8 bw[4][4];
#pragma unroll
    for (int kk = 0; kk < 4; ++kk)
#pragma unroll
        for (int nt = 0; nt < 4; ++nt)
            bw[kk][nt] = *(const sx8*)(WinT + (wave * 64 + nt * 16 + m16) * CC + kk * 32 + q * 8);

    // ---- stage hv tile: fp32 copy + bf16 copy (1 chunk/thread) ----
    {
        int row = tid >> 5;                          // 32 chunks/row
        int c4  = (tid & 31) * 4;
        float4 v = *(const float4*)(hv + (bn * 16 + row) * CC + c4);
        hvF[row * 132 + c4]     = v.x;
        hvF[row * 132 + c4 + 1] = v.y;
        hvF[row * 132 + c4 + 2] = v.z;
        hvF[row * 132 + c4 + 3] = v.w;
        Abf[row * 136 + c4]     = f2bs(v.x);
        Abf[row * 136 + c4 + 1] = f2bs(v.y);
        Abf[row * 136 + c4 + 2] = f2bs(v.z);
        Abf[row * 136 + c4 + 3] = f2bs(v.w);
    }
    __syncthreads();

    // ---- GEMM1: hidden cols [64w, 64w+64) (B all in registers) ----
    fx4 acc1[4];
#pragma unroll
    for (int nt = 0; nt < 4; ++nt)
#pragma unroll
        for (int r = 0; r < 4; ++r) acc1[nt][r] = 0.0f;
#pragma unroll
    for (int kk = 0; kk < 4; ++kk) {
        sx8 af = *(const sx8*)(Abf + m16 * 136 + kk * 32 + q * 8);
#pragma unroll
        for (int nt = 0; nt < 4; ++nt)
            acc1[nt] = __builtin_amdgcn_mfma_f32_16x16x32_bf16(af, bw[kk][nt], acc1[nt], 0, 0, 0);
    }

    // ---- prefetch GEMM2 B-frags (overlap epilogue + barrier) ----
    sx8 c0a[16];
#pragma unroll
    for (int kk = 0; kk < 16; ++kk)
        c0a[kk] = *(const sx8*)(WoutT + col * FFD + kk * 32 + q * 8);

#pragma unroll
    for (int nt = 0; nt < 4; ++nt) {
        int coln = wave * 64 + nt * 16 + m16;
        float bi = Winb[coln];
#pragma unroll
        for (int r = 0; r < 4; ++r) {
            int row = q * 4 + r;
            Xs[row * 520 + coln] = f2bs(gelu_f(acc1[nt][r] + bi));
        }
    }
    __syncthreads();

    // ---- GEMM2: out col (wave*16+m16) (B all in registers) ----
    fx4 o0;
#pragma unroll
    for (int r = 0; r < 4; ++r) o0[r] = 0.0f;
#pragma unroll
    for (int kk = 0; kk < 16; ++kk) {
        sx8 af = *(const sx8*)(Xs + m16 * 520 + kk * 32 + q * 8);
        o0 = __builtin_amdgcn_mfma_f32_16x16x32_bf16(af, c0a[kk], o0, 0, 0, 0);
    }
    {
        float bo = Woutb[col];
#pragma unroll
        for (int r = 0; r < 4; ++r)
            hvF[(q * 4 + r) * 132 + col] += o0[r] + bo;
    }
    __syncthreads();

    // ---- per-node LN2 + mask (16 groups x 32 lanes, single pass) ----
    {
        int g = tid >> 5, l32 = tid & 31;
        int row = g;
        float x0 = hvF[row * 132 + l32];
        float x1 = hvF[row * 132 + l32 + 32];
        float x2 = hvF[row * 132 + l32 + 64];
        float x3 = hvF[row * 132 + l32 + 96];
        float s1 = x0 + x1 + x2 + x3;
        float s2 = x0 * x0 + x1 * x1 + x2 * x2 + x3 * x3;
#pragma unroll
        for (int m = 16; m >= 1; m >>= 1) {
            s1 += __shfl_xor(s1, m, 32);
            s2 += __shfl_xor(s2, m, 32);
        }
        float mean = s1 * (1.0f / 128.0f);
        float var  = s2 * (1.0f / 128.0f) - mean * mean;
        float rstd = rsqrtf(fmaxf(var, 0.0f) + 1e-5f);
        int node = bn * 16 + row;
        float mk = maskV[node];
        float* orow = hv + node * CC;
        float y0 = mk * (g2[l32] * (x0 - mean) * rstd + b2[l32]);
        float y1 = mk * (g2[l32 + 32] * (x1 - mean) * rstd + b2[l32 + 32]);
        float y2 = mk * (g2[l32 + 64] * (x2 - mean) * rstd + b2[l32 + 64]);
        float y3 = mk * (g2[l32 + 96] * (x3 - mean) * rstd + b2[l32 + 96]);
        orow[l32]      = y0;
        orow[l32 + 32] = y1;
        orow[l32 + 64] = y2;
        orow[l32 + 96] = y3;
        Abf[row * 136 + l32]      = f2bs(y0);
        Abf[row * 136 + l32 + 32] = f2bs(y1);
        Abf[row * 136 + l32 + 64] = f2bs(y2);
        Abf[row * 136 + l32 + 96] = f2bs(y3);
    }
    __syncthreads();   // Abf = final hv tile (bf16)

    // ---- fused pass-2 precompute: Pc/Pn col (wave*16+m16) ----
    {
        fx4 pcA, pnA;
#pragma unroll
        for (int r = 0; r < 4; ++r) { pcA[r] = 0.f; pnA[r] = 0.f; }
#pragma unroll
        for (int kk = 0; kk < 4; ++kk) {
            sx8 af  = *(const sx8*)(Abf + m16 * 136 + kk * 32 + q * 8);
            sx8 bc  = *(const sx8*)(W11T + col * K3 + kk * 32 + q * 8);
            sx8 bns = *(const sx8*)(W11T + col * K3 + 256 + kk * 32 + q * 8);
            pcA = __builtin_amdgcn_mfma_f32_16x16x32_bf16(af, bc, pcA, 0, 0, 0);
            pnA = __builtin_amdgcn_mfma_f32_16x16x32_bf16(af, bns, pnA, 0, 0, 0);
        }
        float bi = b11[col];
#pragma unroll
        for (int r = 0; r < 4; ++r) {
            int node = bn * 16 + q * 4 + r;
            Pc[(size_t)node * CC + col] = pcA[r] + bi;
            Pn[(size_t)node * CC + col] = pnA[r];
        }
    }
}

extern "C" void kernel_launch(void* const* d_in, const int* in_sizes, int n_in,
                              void* d_out, int out_size, void* d_ws, size_t ws_size,
                              hipStream_t stream) {
    (void)in_sizes; (void)n_in; (void)out_size; (void)ws_size;
    const float* hV    = (const float*)d_in[0];
    const float* hE    = (const float*)d_in[1];
    const int*   Eidx  = (const int*)d_in[2];
    const float* maskV = (const float*)d_in[3];
    const float* maskA = (const float*)d_in[4];
    const float* W1w  = (const float*)d_in[5];
    const float* W1b  = (const float*)d_in[6];
    const float* W2w  = (const float*)d_in[7];
    const float* W2b  = (const float*)d_in[8];
    const float* W3w  = (const float*)d_in[9];
    const float* W3b  = (const float*)d_in[10];
    const float* W11w = (const float*)d_in[11];
    const float* W11b = (const float*)d_in[12];
    const float* W12w = (const float*)d_in[13];
    const float* W12b = (const float*)d_in[14];
    const float* W13w = (const float*)d_in[15];
    const float* W13b = (const float*)d_in[16];
    const float* Winw = (const float*)d_in[17];
    const float* Winb = (const float*)d_in[18];
    const float* Woutw = (const float*)d_in[19];
    const float* Woutb = (const float*)d_in[20];
    const float* g1 = (const float*)d_in[21];
    const float* b1 = (const float*)d_in[22];
    const float* g2 = (const float*)d_in[23];
    const float* b2 = (const float*)d_in[24];
    const float* g3 = (const float*)d_in[25];
    const float* b3 = (const float*)d_in[26];

    short* wt   = (short*)d_ws;                    // 294912 bf16 = 576KB
    float* Pc   = (float*)((char*)d_ws + 589824);  // [4096,128] fp32 = 2MB
    float* Pn   = Pc + (size_t)BB * NN * CC;       // [4096,128] fp32 = 2MB
    float* outV = (float*)d_out;                   // h_V region [4096,128]
    float* outE = outV + (size_t)BB * NN * CC;     // h_E region [4096,48,128]

    prep_weights<<<72, 256, 0, stream>>>(W1w, W2w, W3w, W11w, W12w, W13w, Winw, Woutw, wt);
    precompute_P<<<256, 256, 0, stream>>>(hV, wt, W1b, Pc, Pn);
    edge_pass<1><<<BB * NN, 256, 0, stream>>>(hV, hE, Eidx,
                                              wt, wt + 49152, W2b, wt + 65536, W3b,
                                              Pc, Pn, maskA, outV, g1, b1, nullptr);
    ffn_kernel<<<256, 512, 0, stream>>>(outV, wt + 163840, Winb, wt + 229376, Woutb, g2, b2, maskV,
                                        wt + 81920, W11b, Pc, Pn);
    edge_pass<2><<<BB * NN, 256, 0, stream>>>(outV, hE, Eidx,
                                              wt + 81920, wt + 131072, W12b, wt + 147456, W13b,
                                              Pc, Pn, nullptr, nullptr, g3, b3, outE);
}